// Round 16
// baseline (61.504 us; speedup 1.0000x reference)
//
#include <hip/hip_runtime.h>
#include <math.h>

typedef unsigned short u16;
typedef u16 u16x4 __attribute__((ext_vector_type(4)));
typedef u16 u16x8 __attribute__((ext_vector_type(8)));
typedef float f32x4 __attribute__((ext_vector_type(4)));
typedef float f32x16 __attribute__((ext_vector_type(16)));
typedef __bf16 bf16x8 __attribute__((ext_vector_type(8)));

#define KC 8
#define K2L 2304  // 256*9

__device__ __forceinline__ u16 f2bf_rne(float f) {
  unsigned u = __float_as_uint(f);
  u += 0x7FFFu + ((u >> 16) & 1u);
  return (u16)(u >> 16);
}

// async global->LDS, 16B/lane; LDS dest is the WAVE-UNIFORM base (HW adds lane*16)
__device__ __forceinline__ void gload16(const u16* g, u16* l) {
  __builtin_amdgcn_global_load_lds(
      (const __attribute__((address_space(1))) unsigned*)g,
      (__attribute__((address_space(3))) unsigned*)l, 16, 0, 0);
}
__device__ __forceinline__ void vmwait0() {
  asm volatile("s_waitcnt vmcnt(0)" ::: "memory");
}

// ---- merged prep: bf16-cast x, bf16-cast W1, build Wc1, Wc2 ----
__device__ __forceinline__ void split4hi(const float* X, u16* hi, int i) {
  f32x4 v = ((const f32x4*)X)[i];
  u16x4 h;
#pragma unroll
  for (int c = 0; c < 4; ++c) h[c] = f2bf_rne(v[c]);
  ((u16x4*)hi)[i] = h;
}
__device__ __forceinline__ void wc_one(const float* coef, const float* sb, const float* sp,
                                       const float* mask, u16* W, int N, int idx) {
  int o = idx / K2L;
  int r = idx - o * K2L;
  int i = r / 9;
  int c = r - i * 9;
  int io = i * N + o;
  float m = mask[io];
  float v = (c == 0) ? m * sb[io] : m * sp[io] * coef[(size_t)io * KC + (c - 1)];
  W[idx] = f2bf_rne(v);
}

__global__ void prep_kernel(const float* __restrict__ x, const float* __restrict__ W1,
                            const float* __restrict__ coef1, const float* __restrict__ sb1,
                            const float* __restrict__ sp1, const float* __restrict__ mask1,
                            const float* __restrict__ coef2, const float* __restrict__ sb2,
                            const float* __restrict__ sp2, const float* __restrict__ mask2,
                            u16* __restrict__ xs_hi, u16* __restrict__ w1_hi,
                            u16* __restrict__ wc1, u16* __restrict__ wc2) {
  const int b = blockIdx.x, tid = threadIdx.x;
  if (b < 4096) {
    split4hi(x, xs_hi, b * 256 + tid);
  } else if (b < 4096 + 256) {
    split4hi(W1, w1_hi, (b - 4096) * 256 + tid);
  } else if (b < 4096 + 256 + 2304) {
    wc_one(coef1, sb1, sp1, mask1, wc1, 256, (b - 4352) * 256 + tid);
  } else {
    wc_one(coef2, sb2, sp2, mask2, wc2, 128, (b - 6656) * 256 + tid);
  }
}

// ---- spline tables + divide-free expand ----
struct Spl {
  float g[12];
  float d1[11], d2[10], d3[9];
};
__device__ __forceinline__ void spl_init(const float* __restrict__ grid, Spl& sp) {
#pragma unroll
  for (int j = 0; j < 12; ++j) sp.g[j] = grid[j];
#pragma unroll
  for (int j = 0; j < 11; ++j) sp.d1[j] = 1.0f / (sp.g[j + 1] - sp.g[j]);
#pragma unroll
  for (int j = 0; j < 10; ++j) sp.d2[j] = 1.0f / (sp.g[j + 2] - sp.g[j]);
#pragma unroll
  for (int j = 0; j < 9; ++j) sp.d3[j] = 1.0f / (sp.g[j + 3] - sp.g[j]);
}
__device__ __forceinline__ void expand_one(float v, const Spl& sp, u16* dst) {
  float Bv[11];
#pragma unroll
  for (int j = 0; j < 11; ++j) Bv[j] = (v >= sp.g[j] && v < sp.g[j + 1]) ? 1.0f : 0.0f;
#pragma unroll
  for (int j = 0; j < 10; ++j)
    Bv[j] = (v - sp.g[j]) * sp.d1[j] * Bv[j] + (sp.g[j + 2] - v) * sp.d1[j + 1] * Bv[j + 1];
#pragma unroll
  for (int j = 0; j < 9; ++j)
    Bv[j] = (v - sp.g[j]) * sp.d2[j] * Bv[j] + (sp.g[j + 3] - v) * sp.d2[j + 1] * Bv[j + 1];
#pragma unroll
  for (int j = 0; j < 8; ++j)
    Bv[j] = (v - sp.g[j]) * sp.d3[j] * Bv[j] + (sp.g[j + 4] - v) * sp.d3[j + 1] * Bv[j + 1];
  dst[0] = f2bf_rne(v / (1.0f + __expf(-v)));  // silu
#pragma unroll
  for (int k = 0; k < 8; ++k) dst[1 + k] = f2bf_rne(Bv[k]);
}

// ---- 8-wave MFMA GEMM, SUPER-STEP pipeline (barrier per 2 K-steps) ----
// BM=MQ*32, BN=NQ*32; 8 waves = (MQ*NQ) spatial quadrants x KG K-groups.
// BK=128 buffers, 4-buf ring as two PAIRS {0,1},{2,3}.  Super-step s consumes
// pair P=s&1 (K-steps 2s,2s+1):
//   vmwait(0) -> s_barrier -> stage pair P^1 (K-steps 2s+2,2s+3)
//   -> ds_read both bufs -> 8 MFMA.
// Safety: pair P^1 was last read at super-step s-1; those ds_reads completed
// (MFMA data-dep) before each wave passed barrier s; the overwriting stage is
// issued after barrier s -> race-free.  vmwait(0) coverage: its loads were
// issued right after barrier s-1 and had a full super-step to land.
// Staging: linear LDS dest + inverse-swizzled global SOURCE + swizzled READ
// (16 slots/row XOR row&15).
// Epilogue KG=2: symmetric kg exchange (both add; f32 commutative) then expand
// split r<8 / r>=8 across kg.  KG=4: 2-round reduction to kg0.
template <int MQ, int NQ, int KG, bool EXPAND>
__global__ __launch_bounds__(512) void gemmW(
    const u16* __restrict__ A0, const u16* __restrict__ B0,
    const float* __restrict__ bias, const float* __restrict__ grid,
    void* __restrict__ outv, int M, int N, int K, int nsteps) {
  static_assert(MQ * NQ * KG == 8, "8 waves");
  constexpr int BM = MQ * 32, BN = NQ * 32;
  constexpr int ASZ = BM * 128;              // u16
  constexpr int BUF_U16 = (BM + BN) * 128;
  constexpr int LPT = (BM + BN) * 16 / 512;  // gloads per thread per stage
  constexpr int SPK = 8 / KG;                // K-16 slices per kg
  __shared__ __align__(16) u16 smu[4 * BUF_U16];

  const int tid = threadIdx.x;
  const int lane = tid & 63;
  const int wid = tid >> 6;
  const int q = wid % (MQ * NQ);
  const int kg = wid / (MQ * NQ);
  const int mq = (NQ == 2) ? (q >> 1) : q;
  const int nq = (NQ == 2) ? (q & 1) : 0;

  // XCD-aware swizzle (grid sizes are multiples of 8)
  const int nb = N / BN;
  const int nwg = (M / BM) * nb;
  const int bid = blockIdx.x;
  const int swz = (bid & 7) * (nwg >> 3) + (bid >> 3);
  const int tm = (swz / nb) * BM;
  const int tn = (swz % nb) * BN;

  const u16* pA0 = A0 + (size_t)tm * K;
  const u16* pB0 = B0 + (size_t)tn * K;

  // chunk c: A if c < BM*16 (row c>>4) else B (row (c-BM*16)>>4); slot=c&15
  // sources k-group slot^(row&15).  LDS linear dest offset = c*16B.
  int srcO[LPT];
  bool isA[LPT];
#pragma unroll
  for (int k = 0; k < LPT; ++k) {
    int c = tid + k * 512;
    bool a = c < BM * 16;
    int r = a ? (c >> 4) : ((c - BM * 16) >> 4);
    int sl = c & 15;
    isA[k] = a;
    srcO[k] = r * K + (((sl ^ (r & 15)) & 15) << 3);  // u16 units
  }

  const int lr = lane & 31;
  const int khf = lane >> 5;

  // swizzled LDS read offsets (u16): row*128 + ((slot^(row&15))&15)*8,
  // slot = slice*2 + khf, slice = kg*SPK + s
  int offA[SPK], offB[SPK];
#pragma unroll
  for (int s = 0; s < SPK; ++s) {
    int slice = kg * SPK + s;
    int rowA = mq * 32 + lr;
    int rowB = nq * 32 + lr;
    offA[s] = rowA * 128 + ((((slice * 2 + khf) ^ (rowA & 15)) & 15) << 3);
    offB[s] = rowB * 128 + ((((slice * 2 + khf) ^ (rowB & 15)) & 15) << 3);
  }

  auto stage = [&](int buf, int step) {
    int kk = step << 7;
    u16* sb = smu + buf * BUF_U16;
#pragma unroll
    for (int k = 0; k < LPT; ++k)
      gload16((isA[k] ? pA0 : pB0) + srcO[k] + kk, sb + (k * 512 + wid * 64) * 8);
  };

  f32x16 acc0 = {}, acc1 = {};
  stage(0, 0);
  stage(1, 1);
  const int S2 = nsteps >> 1;
  for (int s = 0; s < S2; ++s) {
    vmwait0();  // my pair-P loads landed (issued post-barrier at s-1)
    __builtin_amdgcn_sched_barrier(0);
    __builtin_amdgcn_s_barrier();  // all waves' pair-P loads landed;
                                   // pair P^1's s-1 readers done pre-barrier
    __builtin_amdgcn_sched_barrier(0);
    const int P = s & 1;
    if (s + 1 < S2) {  // stage next pair early: max latency coverage
      stage(2 * (P ^ 1), 2 * s + 2);
      stage(2 * (P ^ 1) + 1, 2 * s + 3);
    }

    const u16* sb0 = smu + (2 * P) * BUF_U16;
    const u16* sb1 = smu + (2 * P + 1) * BUF_U16;
    bf16x8 af[2][SPK], bfr[2][SPK];
#pragma unroll
    for (int ss = 0; ss < SPK; ++ss) {
      af[0][ss] = *(const bf16x8*)(sb0 + offA[ss]);
      bfr[0][ss] = *(const bf16x8*)(sb0 + ASZ + offB[ss]);
    }
#pragma unroll
    for (int ss = 0; ss < SPK; ++ss) {
      af[1][ss] = *(const bf16x8*)(sb1 + offA[ss]);
      bfr[1][ss] = *(const bf16x8*)(sb1 + ASZ + offB[ss]);
    }
    // buf 2P fully, then 2P+1: accumulation order bit-identical to R15
#pragma unroll
    for (int j = 0; j < 2; ++j)
#pragma unroll
      for (int ss = 0; ss < SPK; ++ss) {
        f32x16& ac = (ss & 1) ? acc1 : acc0;  // 2 chains for MFMA ILP
        ac = __builtin_amdgcn_mfma_f32_32x32x16_bf16(af[j][ss], bfr[j][ss], ac, 0, 0, 0);
      }
  }
  f32x16 accv = acc0 + acc1;

  // C/D layout (m74/m101): col = lane&31, row = (r&3) + 8*(r>>2) + 4*(lane>>5)
  const int rbase = 4 * khf;
  const int rowq = mq * 32, colq = nq * 32;

  float* Fr = (float*)smu;
  if constexpr (KG == 2) {
    // symmetric exchange: both kgs end up with the full sum (f32 + commutative)
    __syncthreads();
#pragma unroll
    for (int r = 0; r < 16; ++r) {
      int row = rowq + rbase + (r & 3) + 8 * (r >> 2);
      Fr[kg * (BM * BN) + row * BN + colq + lr] = accv[r];
    }
    __syncthreads();
#pragma unroll
    for (int r = 0; r < 16; ++r) {
      int row = rowq + rbase + (r & 3) + 8 * (r >> 2);
      accv[r] += Fr[(1 - kg) * (BM * BN) + row * BN + colq + lr];
    }
  } else {
    // 2-round reduction to kg0 (R12-proven)
    __syncthreads();
    if (kg >= 2) {
#pragma unroll
      for (int r = 0; r < 16; ++r) {
        int row = rowq + rbase + (r & 3) + 8 * (r >> 2);
        Fr[(kg - 2) * (BM * BN) + row * BN + colq + lr] = accv[r];
      }
    }
    __syncthreads();
    if (kg < 2) {
#pragma unroll
      for (int r = 0; r < 16; ++r) {
        int row = rowq + rbase + (r & 3) + 8 * (r >> 2);
        accv[r] += Fr[kg * (BM * BN) + row * BN + colq + lr];
      }
    }
    __syncthreads();
    if (kg == 1) {
#pragma unroll
      for (int r = 0; r < 16; ++r) {
        int row = rowq + rbase + (r & 3) + 8 * (r >> 2);
        Fr[row * BN + colq + lr] = accv[r];
      }
    }
    __syncthreads();
    if (kg == 0) {
#pragma unroll
      for (int r = 0; r < 16; ++r) {
        int row = rowq + rbase + (r & 3) + 8 * (r >> 2);
        accv[r] += Fr[row * BN + colq + lr];
      }
    }
  }

  if constexpr (EXPAND) {
    Spl sp;
    spl_init(grid, sp);
    __syncthreads();  // Fr reads done before F-tile overwrite
    u16* Fl = smu;
    {
      int col = colq + lr;
      float bv = bias ? bias[tn + col] : 0.0f;
      // split the serial spline chain across kg: kg0 -> r<8, kg1 -> r>=8
      const int r0 = kg * 8, r1 = r0 + 8;
#pragma unroll
      for (int r = 0; r < 16; ++r) {
        if (r >= r0 && r < r1) {
          int row = rowq + rbase + (r & 3) + 8 * (r >> 2);
          expand_one(accv[r] + bv, sp, Fl + (size_t)row * (BN * 9) + col * 9);
        }
      }
    }
    __syncthreads();
    // coalesced copy-out: BM x (BN*9) bf16 in 16B chunks, all 512 threads
    u16* Fout = (u16*)outv;
    constexpr int RB = BN * 9 / 8;
    constexpr int CH = BM * RB;
    const size_t fstride = (size_t)N * 9;
    for (int ch = tid; ch < CH; ch += 512) {
      int r = ch / RB, o = ch - r * RB;
      *(u16x8*)(Fout + (size_t)(tm + r) * fstride + (size_t)tn * 9 + o * 8) =
          *(const u16x8*)(Fl + (size_t)ch * 8);
    }
  } else {
    if (kg == 0) {
      float* Cp = (float*)outv;
      const int cbase = tn + colq + lr;
#pragma unroll
      for (int r = 0; r < 16; ++r) {
        int row = tm + rowq + rbase + (r & 3) + 8 * (r >> 2);
        Cp[(size_t)row * N + cbase] = accv[r];
      }
    }
  }
}

extern "C" void kernel_launch(void* const* d_in, const int* in_sizes, int n_in,
                              void* d_out, int out_size, void* d_ws, size_t ws_size,
                              hipStream_t stream) {
  (void)in_sizes; (void)n_in; (void)out_size; (void)ws_size;
  const float* x     = (const float*)d_in[0];   // 4096x1024
  const float* W1    = (const float*)d_in[1];   // 256x1024
  const float* b1    = (const float*)d_in[2];   // 256
  const float* grid1 = (const float*)d_in[3];   // 256x12 (rows identical)
  const float* coef1 = (const float*)d_in[4];   // 256x256x8
  const float* sb1   = (const float*)d_in[5];
  const float* sp1   = (const float*)d_in[6];
  const float* mask1 = (const float*)d_in[7];
  const float* grid2 = (const float*)d_in[8];
  const float* coef2 = (const float*)d_in[9];   // 256x128x8
  const float* sb2   = (const float*)d_in[10];
  const float* sp2   = (const float*)d_in[11];
  const float* mask2 = (const float*)d_in[12];
  float* outp = (float*)d_out;

  char* ws = (char*)d_ws;
  size_t off = 0;
  auto alloc = [&](size_t bytes) {
    char* p = ws + off;
    off += (bytes + 255) & ~(size_t)255;
    return (void*)p;
  };
  u16* xs_hi  = (u16*)alloc((size_t)4096 * 1024 * 2);
  u16* w1_hi  = (u16*)alloc((size_t)256 * 1024 * 2);
  u16* wc1    = (u16*)alloc((size_t)256 * K2L * 2);
  u16* wc2    = (u16*)alloc((size_t)128 * K2L * 2);
  u16* F1     = (u16*)alloc((size_t)4096 * K2L * 2);
  u16* F2     = (u16*)alloc((size_t)4096 * K2L * 2);

  // merged prep (all bf16 casts + Wc builds)
  prep_kernel<<<7808, 256, 0, stream>>>(x, W1, coef1, sb1, sp1, mask1,
                                        coef2, sb2, sp2, mask2,
                                        xs_hi, w1_hi, wc1, wc2);

  // L1: F1 = expand(x_bf @ W1_bf^T + b1); K=1024 -> 8 steps (4 super); grid 256
  gemmW<2, 2, 2, true><<<256, 512, 0, stream>>>(
      xs_hi, w1_hi, b1, grid1, F1, 4096, 256, 1024, 8);

  // L2: F2 = expand(F1 @ Wc1^T); K=2304 -> 18 steps (9 super); grid 256
  gemmW<2, 2, 2, true><<<256, 512, 0, stream>>>(
      F1, wc1, nullptr, grid2, F2, 4096, 256, 2304, 18);

  // L3: out = F2 @ Wc2^T; K=2304, N=128; BM=64 BN=32 -> grid 256
  gemmW<2, 1, 4, false><<<256, 512, 0, stream>>>(
      F2, wc2, nullptr, nullptr, outp, 4096, 128, 2304, 18);
}

// Round 17
// 60.601 us; speedup vs baseline: 1.0149x; 1.0149x over previous
//
#include <hip/hip_runtime.h>
#include <math.h>

typedef unsigned short u16;
typedef u16 u16x4 __attribute__((ext_vector_type(4)));
typedef u16 u16x8 __attribute__((ext_vector_type(8)));
typedef float f32x4 __attribute__((ext_vector_type(4)));
typedef float f32x16 __attribute__((ext_vector_type(16)));
typedef __bf16 bf16x8 __attribute__((ext_vector_type(8)));

#define KC 8
#define K2L 2304  // 256*9

__device__ __forceinline__ u16 f2bf_rne(float f) {
  unsigned u = __float_as_uint(f);
  u += 0x7FFFu + ((u >> 16) & 1u);
  return (u16)(u >> 16);
}

// async global->LDS, 16B/lane; LDS dest is the WAVE-UNIFORM base (HW adds lane*16)
__device__ __forceinline__ void gload16(const u16* g, u16* l) {
  __builtin_amdgcn_global_load_lds(
      (const __attribute__((address_space(1))) unsigned*)g,
      (__attribute__((address_space(3))) unsigned*)l, 16, 0, 0);
}
template <int N>
__device__ __forceinline__ void vmwait() {
  if constexpr (N == 0)      asm volatile("s_waitcnt vmcnt(0)" ::: "memory");
  else if constexpr (N == 3) asm volatile("s_waitcnt vmcnt(3)" ::: "memory");
  else if constexpr (N == 4) asm volatile("s_waitcnt vmcnt(4)" ::: "memory");
  else if constexpr (N == 6) asm volatile("s_waitcnt vmcnt(6)" ::: "memory");
  else if constexpr (N == 8) asm volatile("s_waitcnt vmcnt(8)" ::: "memory");
  else static_assert(N == 0, "unsupported vmcnt literal");
}

// ---- slim prep: build Wc1, Wc2 only (x/W1 conversion fused into L1) ----
__device__ __forceinline__ void wc_one(const float* coef, const float* sb, const float* sp,
                                       const float* mask, u16* W, int N, int idx) {
  int o = idx / K2L;
  int r = idx - o * K2L;
  int i = r / 9;
  int c = r - i * 9;
  int io = i * N + o;
  float m = mask[io];
  float v = (c == 0) ? m * sb[io] : m * sp[io] * coef[(size_t)io * KC + (c - 1)];
  W[idx] = f2bf_rne(v);
}

__global__ void prep_wc_kernel(const float* __restrict__ coef1, const float* __restrict__ sb1,
                               const float* __restrict__ sp1, const float* __restrict__ mask1,
                               const float* __restrict__ coef2, const float* __restrict__ sb2,
                               const float* __restrict__ sp2, const float* __restrict__ mask2,
                               u16* __restrict__ wc1, u16* __restrict__ wc2) {
  const int b = blockIdx.x, tid = threadIdx.x;
  if (b < 2304) {
    wc_one(coef1, sb1, sp1, mask1, wc1, 256, b * 256 + tid);
  } else {
    wc_one(coef2, sb2, sp2, mask2, wc2, 128, (b - 2304) * 256 + tid);
  }
}

// ---- spline tables + divide-free expand ----
struct Spl {
  float g[12];
  float d1[11], d2[10], d3[9];
};
__device__ __forceinline__ void spl_init(const float* __restrict__ grid, Spl& sp) {
#pragma unroll
  for (int j = 0; j < 12; ++j) sp.g[j] = grid[j];
#pragma unroll
  for (int j = 0; j < 11; ++j) sp.d1[j] = 1.0f / (sp.g[j + 1] - sp.g[j]);
#pragma unroll
  for (int j = 0; j < 10; ++j) sp.d2[j] = 1.0f / (sp.g[j + 2] - sp.g[j]);
#pragma unroll
  for (int j = 0; j < 9; ++j) sp.d3[j] = 1.0f / (sp.g[j + 3] - sp.g[j]);
}
__device__ __forceinline__ void expand_one(float v, const Spl& sp, u16* dst) {
  float Bv[11];
#pragma unroll
  for (int j = 0; j < 11; ++j) Bv[j] = (v >= sp.g[j] && v < sp.g[j + 1]) ? 1.0f : 0.0f;
#pragma unroll
  for (int j = 0; j < 10; ++j)
    Bv[j] = (v - sp.g[j]) * sp.d1[j] * Bv[j] + (sp.g[j + 2] - v) * sp.d1[j + 1] * Bv[j + 1];
#pragma unroll
  for (int j = 0; j < 9; ++j)
    Bv[j] = (v - sp.g[j]) * sp.d2[j] * Bv[j] + (sp.g[j + 3] - v) * sp.d2[j + 1] * Bv[j + 1];
#pragma unroll
  for (int j = 0; j < 8; ++j)
    Bv[j] = (v - sp.g[j]) * sp.d3[j] * Bv[j] + (sp.g[j + 4] - v) * sp.d3[j + 1] * Bv[j + 1];
  dst[0] = f2bf_rne(v / (1.0f + __expf(-v)));  // silu
#pragma unroll
  for (int k = 0; k < 8; ++k) dst[1 + k] = f2bf_rne(Bv[k]);
}

// ---- 8-wave MFMA GEMM (R15-proven pipeline; used for L2/L3) ----
// BM=MQ*32, BN=NQ*32; 8 waves = (MQ*NQ) spatial quadrants x KG K-groups.
// BK=128; 4-buf ring, depth-2 prefetch, counted vmcnt, ONE s_barrier/step.
// Staging: linear LDS dest + inverse-swizzled global SOURCE + swizzled READ
// (16 slots/row XOR row&15).
// Epilogue KG=2: symmetric kg exchange then expand split r<8/r>=8 across kg.
// KG=4: 2-round reduction to kg0.
template <int MQ, int NQ, int KG, bool EXPAND>
__global__ __launch_bounds__(512) void gemmW(
    const u16* __restrict__ A0, const u16* __restrict__ B0,
    const float* __restrict__ bias, const float* __restrict__ grid,
    void* __restrict__ outv, int M, int N, int K, int nsteps) {
  static_assert(MQ * NQ * KG == 8, "8 waves");
  constexpr int BM = MQ * 32, BN = NQ * 32;
  constexpr int ASZ = BM * 128;              // u16
  constexpr int BUF_U16 = (BM + BN) * 128;
  constexpr int LPT = (BM + BN) * 16 / 512;  // gloads per thread per stage
  constexpr int SPK = 8 / KG;                // K-16 slices per kg
  __shared__ __align__(16) u16 smu[4 * BUF_U16];

  const int tid = threadIdx.x;
  const int lane = tid & 63;
  const int wid = tid >> 6;
  const int q = wid % (MQ * NQ);
  const int kg = wid / (MQ * NQ);
  const int mq = (NQ == 2) ? (q >> 1) : q;
  const int nq = (NQ == 2) ? (q & 1) : 0;

  const int nb = N / BN;
  const int nwg = (M / BM) * nb;
  const int bid = blockIdx.x;
  const int swz = (bid & 7) * (nwg >> 3) + (bid >> 3);
  const int tm = (swz / nb) * BM;
  const int tn = (swz % nb) * BN;

  const u16* pA0 = A0 + (size_t)tm * K;
  const u16* pB0 = B0 + (size_t)tn * K;

  int srcO[LPT];
  bool isA[LPT];
#pragma unroll
  for (int k = 0; k < LPT; ++k) {
    int c = tid + k * 512;
    bool a = c < BM * 16;
    int r = a ? (c >> 4) : ((c - BM * 16) >> 4);
    int sl = c & 15;
    isA[k] = a;
    srcO[k] = r * K + (((sl ^ (r & 15)) & 15) << 3);  // u16 units
  }

  const int lr = lane & 31;
  const int khf = lane >> 5;

  int offA[SPK], offB[SPK];
#pragma unroll
  for (int s = 0; s < SPK; ++s) {
    int slice = kg * SPK + s;
    int rowA = mq * 32 + lr;
    int rowB = nq * 32 + lr;
    offA[s] = rowA * 128 + ((((slice * 2 + khf) ^ (rowA & 15)) & 15) << 3);
    offB[s] = rowB * 128 + ((((slice * 2 + khf) ^ (rowB & 15)) & 15) << 3);
  }

  auto stage = [&](int buf, int step) {
    int kk = step << 7;
    u16* sb = smu + buf * BUF_U16;
#pragma unroll
    for (int k = 0; k < LPT; ++k)
      gload16((isA[k] ? pA0 : pB0) + srcO[k] + kk, sb + (k * 512 + wid * 64) * 8);
  };

  f32x16 acc0 = {}, acc1 = {};
  stage(0, 0);
  stage(1, 1);
  for (int i = 0; i < nsteps; ++i) {
    if (i + 2 < nsteps) {
      stage((i + 2) & 3, i + 2);
      vmwait<2 * LPT>();  // my LPT loads for buf[i&3] landed (2 stages in flight)
    } else if (i + 1 < nsteps) {
      vmwait<LPT>();
    } else {
      vmwait<0>();
    }
    __builtin_amdgcn_sched_barrier(0);
    __builtin_amdgcn_s_barrier();
    __builtin_amdgcn_sched_barrier(0);

    const u16* sb = smu + (i & 3) * BUF_U16;
    bf16x8 af[SPK], bfr[SPK];
#pragma unroll
    for (int s = 0; s < SPK; ++s) {
      af[s] = *(const bf16x8*)(sb + offA[s]);
      bfr[s] = *(const bf16x8*)(sb + ASZ + offB[s]);
    }
#pragma unroll
    for (int s = 0; s < SPK; ++s) {
      f32x16& ac = (s & 1) ? acc1 : acc0;  // 2 chains for MFMA ILP
      ac = __builtin_amdgcn_mfma_f32_32x32x16_bf16(af[s], bfr[s], ac, 0, 0, 0);
    }
  }
  f32x16 accv = acc0 + acc1;

  // C/D layout (m74/m101): col = lane&31, row = (r&3) + 8*(r>>2) + 4*(lane>>5)
  const int rbase = 4 * khf;
  const int rowq = mq * 32, colq = nq * 32;

  float* Fr = (float*)smu;
  if constexpr (KG == 2) {
    __syncthreads();
#pragma unroll
    for (int r = 0; r < 16; ++r) {
      int row = rowq + rbase + (r & 3) + 8 * (r >> 2);
      Fr[kg * (BM * BN) + row * BN + colq + lr] = accv[r];
    }
    __syncthreads();
#pragma unroll
    for (int r = 0; r < 16; ++r) {
      int row = rowq + rbase + (r & 3) + 8 * (r >> 2);
      accv[r] += Fr[(1 - kg) * (BM * BN) + row * BN + colq + lr];
    }
  } else {
    __syncthreads();
    if (kg >= 2) {
#pragma unroll
      for (int r = 0; r < 16; ++r) {
        int row = rowq + rbase + (r & 3) + 8 * (r >> 2);
        Fr[(kg - 2) * (BM * BN) + row * BN + colq + lr] = accv[r];
      }
    }
    __syncthreads();
    if (kg < 2) {
#pragma unroll
      for (int r = 0; r < 16; ++r) {
        int row = rowq + rbase + (r & 3) + 8 * (r >> 2);
        accv[r] += Fr[kg * (BM * BN) + row * BN + colq + lr];
      }
    }
    __syncthreads();
    if (kg == 1) {
#pragma unroll
      for (int r = 0; r < 16; ++r) {
        int row = rowq + rbase + (r & 3) + 8 * (r >> 2);
        Fr[row * BN + colq + lr] = accv[r];
      }
    }
    __syncthreads();
    if (kg == 0) {
#pragma unroll
      for (int r = 0; r < 16; ++r) {
        int row = rowq + rbase + (r & 3) + 8 * (r >> 2);
        accv[r] += Fr[row * BN + colq + lr];
      }
    }
  }

  if constexpr (EXPAND) {
    Spl sp;
    spl_init(grid, sp);
    __syncthreads();
    u16* Fl = smu;
    {
      int col = colq + lr;
      float bv = bias ? bias[tn + col] : 0.0f;
      const int r0 = kg * 8, r1 = r0 + 8;
#pragma unroll
      for (int r = 0; r < 16; ++r) {
        if (r >= r0 && r < r1) {
          int row = rowq + rbase + (r & 3) + 8 * (r >> 2);
          expand_one(accv[r] + bv, sp, Fl + (size_t)row * (BN * 9) + col * 9);
        }
      }
    }
    __syncthreads();
    u16* Fout = (u16*)outv;
    constexpr int RB = BN * 9 / 8;
    constexpr int CH = BM * RB;
    const size_t fstride = (size_t)N * 9;
    for (int ch = tid; ch < CH; ch += 512) {
      int r = ch / RB, o = ch - r * RB;
      *(u16x8*)(Fout + (size_t)(tm + r) * fstride + (size_t)tn * 9 + o * 8) =
          *(const u16x8*)(Fl + (size_t)ch * 8);
    }
  } else {
    if (kg == 0) {
      float* Cp = (float*)outv;
      const int cbase = tn + colq + lr;
#pragma unroll
      for (int r = 0; r < 16; ++r) {
        int row = tm + rowq + rbase + (r & 3) + 8 * (r >> 2);
        Cp[(size_t)row * N + cbase] = accv[r];
      }
    }
  }
}

// ---- L1: fused-conversion GEMM (f32 x, W1 -> bf16 in staging) ----
// Same geometry/pipeline as gemmW<2,2,2,true> but reg-staged: per 16B LDS
// chunk, load 2x f32x4 from the inverse-swizzled f32 source, cvt to bf16,
// ds_write_b128 to the SAME linear LDS layout.  Register double-buffer
// (ldA/ldB, parity-unrolled).  Write of buf[(i+2)&3] pre-barrier is race-free:
// its previous contents (step i-2) were read before every wave passed
// barrier i-1.  lgkmcnt(0) before each barrier makes writes cross-wave
// visible.  Compiler inserts precise vmcnt waits for the reg path.
__global__ __launch_bounds__(512) void gemmL1(
    const float* __restrict__ X, const float* __restrict__ W,
    const float* __restrict__ bias, const float* __restrict__ grid,
    u16* __restrict__ outF, int M, int N, int K, int nsteps) {
  constexpr int BM = 64, BN = 64;
  constexpr int ASZ = BM * 128;             // u16
  constexpr int BUF_U16 = (BM + BN) * 128;  // 32 KB
  constexpr int SPK = 4;                    // KG=2
  __shared__ __align__(16) u16 smu[4 * BUF_U16];  // 128 KB

  const int tid = threadIdx.x;
  const int lane = tid & 63;
  const int wid = tid >> 6;
  const int q = wid % 4;
  const int kg = wid / 4;
  const int mq = q >> 1, nq = q & 1;

  const int nb = N / BN;
  const int nwg = (M / BM) * nb;
  const int bid = blockIdx.x;
  const int swz = (bid & 7) * (nwg >> 3) + (bid >> 3);
  const int tm = (swz / nb) * BM;
  const int tn = (swz % nb) * BN;

  const float* pX = X + (size_t)tm * K;
  const float* pW = W + (size_t)tn * K;

  int srcO[4];
  bool isA[4];
#pragma unroll
  for (int k = 0; k < 4; ++k) {
    int c = tid + k * 512;
    bool a = c < BM * 16;
    int r = a ? (c >> 4) : ((c - BM * 16) >> 4);
    int sl = c & 15;
    isA[k] = a;
    srcO[k] = r * K + (((sl ^ (r & 15)) & 15) << 3);  // element units (f32 here)
  }

  const int lr = lane & 31;
  const int khf = lane >> 5;
  int offA[SPK], offB[SPK];
#pragma unroll
  for (int s = 0; s < SPK; ++s) {
    int slice = kg * SPK + s;
    int rowA = mq * 32 + lr;
    int rowB = nq * 32 + lr;
    offA[s] = rowA * 128 + ((((slice * 2 + khf) ^ (rowA & 15)) & 15) << 3);
    offB[s] = rowB * 128 + ((((slice * 2 + khf) ^ (rowB & 15)) & 15) << 3);
  }

  f32x4 ldA[4][2], ldB[4][2];
  auto loadsA = [&](int step) {
#pragma unroll
    for (int k = 0; k < 4; ++k) {
      const float* s = (isA[k] ? pX : pW) + srcO[k] + (step << 7);
      ldA[k][0] = *(const f32x4*)s;
      ldA[k][1] = *(const f32x4*)(s + 4);
    }
  };
  auto loadsB = [&](int step) {
#pragma unroll
    for (int k = 0; k < 4; ++k) {
      const float* s = (isA[k] ? pX : pW) + srcO[k] + (step << 7);
      ldB[k][0] = *(const f32x4*)s;
      ldB[k][1] = *(const f32x4*)(s + 4);
    }
  };
  auto writeA = [&](int buf) {
    u16* sb = smu + buf * BUF_U16;
#pragma unroll
    for (int k = 0; k < 4; ++k) {
      u16x8 h;
#pragma unroll
      for (int c = 0; c < 4; ++c) {
        h[c] = f2bf_rne(ldA[k][0][c]);
        h[c + 4] = f2bf_rne(ldA[k][1][c]);
      }
      *(u16x8*)(sb + (size_t)(tid + k * 512) * 8) = h;
    }
  };
  auto writeB = [&](int buf) {
    u16* sb = smu + buf * BUF_U16;
#pragma unroll
    for (int k = 0; k < 4; ++k) {
      u16x8 h;
#pragma unroll
      for (int c = 0; c < 4; ++c) {
        h[c] = f2bf_rne(ldB[k][0][c]);
        h[c + 4] = f2bf_rne(ldB[k][1][c]);
      }
      *(u16x8*)(sb + (size_t)(tid + k * 512) * 8) = h;
    }
  };

  // prologue: buf0,buf1 written; load(2) parked in ldA (consumed at i=0)
  loadsA(0);
  writeA(0);
  loadsA(1);
  writeA(1);
  loadsA(2);

  f32x16 acc0 = {}, acc1 = {};
  for (int i = 0; i < nsteps; ++i) {
    // i even: write from ldA (load i+2), prefetch i+3 into ldB; odd: swapped
    if ((i & 1) == 0) {
      if (i + 3 < nsteps) loadsB(i + 3);
      if (i + 2 < nsteps) writeA((i + 2) & 3);
    } else {
      if (i + 3 < nsteps) loadsA(i + 3);
      if (i + 2 < nsteps) writeB((i + 2) & 3);
    }
    asm volatile("s_waitcnt lgkmcnt(0)" ::: "memory");  // writes visible post-barrier
    __builtin_amdgcn_sched_barrier(0);
    __builtin_amdgcn_s_barrier();  // buf[i&3] (written step i-2) ready for all
    __builtin_amdgcn_sched_barrier(0);

    const u16* sb = smu + (i & 3) * BUF_U16;
    bf16x8 af[SPK], bfr[SPK];
#pragma unroll
    for (int s = 0; s < SPK; ++s) {
      af[s] = *(const bf16x8*)(sb + offA[s]);
      bfr[s] = *(const bf16x8*)(sb + ASZ + offB[s]);
    }
#pragma unroll
    for (int s = 0; s < SPK; ++s) {
      f32x16& ac = (s & 1) ? acc1 : acc0;
      ac = __builtin_amdgcn_mfma_f32_32x32x16_bf16(af[s], bfr[s], ac, 0, 0, 0);
    }
  }
  f32x16 accv = acc0 + acc1;

  const int rbase = 4 * khf;
  const int rowq = mq * 32, colq = nq * 32;

  // symmetric kg exchange (R15 KG=2 path)
  float* Fr = (float*)smu;
  __syncthreads();
#pragma unroll
  for (int r = 0; r < 16; ++r) {
    int row = rowq + rbase + (r & 3) + 8 * (r >> 2);
    Fr[kg * (BM * BN) + row * BN + colq + lr] = accv[r];
  }
  __syncthreads();
#pragma unroll
  for (int r = 0; r < 16; ++r) {
    int row = rowq + rbase + (r & 3) + 8 * (r >> 2);
    accv[r] += Fr[(1 - kg) * (BM * BN) + row * BN + colq + lr];
  }

  Spl sp;
  spl_init(grid, sp);
  __syncthreads();
  u16* Fl = smu;
  {
    int col = colq + lr;
    float bv = bias[tn + col];
    const int r0 = kg * 8, r1 = r0 + 8;
#pragma unroll
    for (int r = 0; r < 16; ++r) {
      if (r >= r0 && r < r1) {
        int row = rowq + rbase + (r & 3) + 8 * (r >> 2);
        expand_one(accv[r] + bv, sp, Fl + (size_t)row * (BN * 9) + col * 9);
      }
    }
  }
  __syncthreads();
  constexpr int RB = BN * 9 / 8;
  constexpr int CH = BM * RB;
  const size_t fstride = (size_t)N * 9;
  for (int ch = tid; ch < CH; ch += 512) {
    int r = ch / RB, o = ch - r * RB;
    *(u16x8*)(outF + (size_t)(tm + r) * fstride + (size_t)tn * 9 + o * 8) =
        *(const u16x8*)(Fl + (size_t)ch * 8);
  }
}

extern "C" void kernel_launch(void* const* d_in, const int* in_sizes, int n_in,
                              void* d_out, int out_size, void* d_ws, size_t ws_size,
                              hipStream_t stream) {
  (void)in_sizes; (void)n_in; (void)out_size; (void)ws_size;
  const float* x     = (const float*)d_in[0];   // 4096x1024
  const float* W1    = (const float*)d_in[1];   // 256x1024
  const float* b1    = (const float*)d_in[2];   // 256
  const float* grid1 = (const float*)d_in[3];   // 256x12 (rows identical)
  const float* coef1 = (const float*)d_in[4];   // 256x256x8
  const float* sb1   = (const float*)d_in[5];
  const float* sp1   = (const float*)d_in[6];
  const float* mask1 = (const float*)d_in[7];
  const float* grid2 = (const float*)d_in[8];
  const float* coef2 = (const float*)d_in[9];   // 256x128x8
  const float* sb2   = (const float*)d_in[10];
  const float* sp2   = (const float*)d_in[11];
  const float* mask2 = (const float*)d_in[12];
  float* outp = (float*)d_out;

  char* ws = (char*)d_ws;
  size_t off = 0;
  auto alloc = [&](size_t bytes) {
    char* p = ws + off;
    off += (bytes + 255) & ~(size_t)255;
    return (void*)p;
  };
  u16* wc1 = (u16*)alloc((size_t)256 * K2L * 2);
  u16* wc2 = (u16*)alloc((size_t)128 * K2L * 2);
  u16* F1  = (u16*)alloc((size_t)4096 * K2L * 2);
  u16* F2  = (u16*)alloc((size_t)4096 * K2L * 2);

  // slim prep: Wc1 + Wc2 only
  prep_wc_kernel<<<3456, 256, 0, stream>>>(coef1, sb1, sp1, mask1,
                                           coef2, sb2, sp2, mask2, wc1, wc2);

  // L1: F1 = expand(bf16(x) @ bf16(W1)^T + b1); fused cvt; K=1024 -> 8 steps
  gemmL1<<<256, 512, 0, stream>>>(x, W1, b1, grid1, F1, 4096, 256, 1024, 8);

  // L2: F2 = expand(F1 @ Wc1^T); K=2304 -> 18 steps; grid 256
  gemmW<2, 2, 2, true><<<256, 512, 0, stream>>>(
      F1, wc1, nullptr, grid2, F2, 4096, 256, 2304, 18);

  // L3: out = F2 @ Wc2^T; K=2304, N=128; BM=64 BN=32 -> grid 256
  gemmW<2, 1, 4, false><<<256, 512, 0, stream>>>(
      F2, wc2, nullptr, nullptr, outp, 4096, 128, 2304, 18);
}

// Round 18
// 58.676 us; speedup vs baseline: 1.0482x; 1.0328x over previous
//
#include <hip/hip_runtime.h>
#include <math.h>

typedef unsigned short u16;
typedef u16 u16x4 __attribute__((ext_vector_type(4)));
typedef u16 u16x8 __attribute__((ext_vector_type(8)));
typedef float f32x4 __attribute__((ext_vector_type(4)));
typedef float f32x16 __attribute__((ext_vector_type(16)));
typedef __bf16 bf16x8 __attribute__((ext_vector_type(8)));

#define KC 8
#define K2L 2304  // 256*9

__device__ __forceinline__ u16 f2bf_rne(float f) {
  unsigned u = __float_as_uint(f);
  u += 0x7FFFu + ((u >> 16) & 1u);
  return (u16)(u >> 16);
}

// async global->LDS, 16B/lane; LDS dest is the WAVE-UNIFORM base (HW adds lane*16)
__device__ __forceinline__ void gload16(const u16* g, u16* l) {
  __builtin_amdgcn_global_load_lds(
      (const __attribute__((address_space(1))) unsigned*)g,
      (__attribute__((address_space(3))) unsigned*)l, 16, 0, 0);
}
template <int N>
__device__ __forceinline__ void vmwait() {
  if constexpr (N == 0)      asm volatile("s_waitcnt vmcnt(0)" ::: "memory");
  else if constexpr (N == 3) asm volatile("s_waitcnt vmcnt(3)" ::: "memory");
  else if constexpr (N == 4) asm volatile("s_waitcnt vmcnt(4)" ::: "memory");
  else if constexpr (N == 6) asm volatile("s_waitcnt vmcnt(6)" ::: "memory");
  else if constexpr (N == 8) asm volatile("s_waitcnt vmcnt(8)" ::: "memory");
  else static_assert(N == 0, "unsupported vmcnt literal");
}

// ---- slim prep: bf16-cast x and W1 only (Wc builds live in GEMM tails) ----
__device__ __forceinline__ void split4hi(const float* X, u16* hi, int i) {
  f32x4 v = ((const f32x4*)X)[i];
  u16x4 h;
#pragma unroll
  for (int c = 0; c < 4; ++c) h[c] = f2bf_rne(v[c]);
  ((u16x4*)hi)[i] = h;
}
__global__ void prep_split_kernel(const float* __restrict__ x, const float* __restrict__ W1,
                                  u16* __restrict__ xs_hi, u16* __restrict__ w1_hi) {
  const int b = blockIdx.x, tid = threadIdx.x;
  if (b < 4096) {
    split4hi(x, xs_hi, b * 256 + tid);
  } else {
    split4hi(W1, w1_hi, (b - 4096) * 256 + tid);
  }
}

// Wc[o][i*9+0] = mask*sb ; Wc[o][i*9+1+k] = mask*sp*coef[i,o,k]
__device__ __forceinline__ void wc_one(const float* coef, const float* sb, const float* sp,
                                       const float* mask, u16* W, int N, int idx) {
  int o = idx / K2L;
  int r = idx - o * K2L;
  int i = r / 9;
  int c = r - i * 9;
  int io = i * N + o;
  float m = mask[io];
  float v = (c == 0) ? m * sb[io] : m * sp[io] * coef[(size_t)io * KC + (c - 1)];
  W[idx] = f2bf_rne(v);
}

// ---- spline tables + divide-free expand ----
struct Spl {
  float g[12];
  float d1[11], d2[10], d3[9];
};
__device__ __forceinline__ void spl_init(const float* __restrict__ grid, Spl& sp) {
#pragma unroll
  for (int j = 0; j < 12; ++j) sp.g[j] = grid[j];
#pragma unroll
  for (int j = 0; j < 11; ++j) sp.d1[j] = 1.0f / (sp.g[j + 1] - sp.g[j]);
#pragma unroll
  for (int j = 0; j < 10; ++j) sp.d2[j] = 1.0f / (sp.g[j + 2] - sp.g[j]);
#pragma unroll
  for (int j = 0; j < 9; ++j) sp.d3[j] = 1.0f / (sp.g[j + 3] - sp.g[j]);
}
__device__ __forceinline__ void expand_one(float v, const Spl& sp, u16* dst) {
  float Bv[11];
#pragma unroll
  for (int j = 0; j < 11; ++j) Bv[j] = (v >= sp.g[j] && v < sp.g[j + 1]) ? 1.0f : 0.0f;
#pragma unroll
  for (int j = 0; j < 10; ++j)
    Bv[j] = (v - sp.g[j]) * sp.d1[j] * Bv[j] + (sp.g[j + 2] - v) * sp.d1[j + 1] * Bv[j + 1];
#pragma unroll
  for (int j = 0; j < 9; ++j)
    Bv[j] = (v - sp.g[j]) * sp.d2[j] * Bv[j] + (sp.g[j + 3] - v) * sp.d2[j + 1] * Bv[j + 1];
#pragma unroll
  for (int j = 0; j < 8; ++j)
    Bv[j] = (v - sp.g[j]) * sp.d3[j] * Bv[j] + (sp.g[j + 4] - v) * sp.d3[j + 1] * Bv[j + 1];
  dst[0] = f2bf_rne(v / (1.0f + __expf(-v)));  // silu
#pragma unroll
  for (int k = 0; k < 8; ++k) dst[1 + k] = f2bf_rne(Bv[k]);
}

// ---- 8-wave MFMA GEMM (R15-proven pipeline) + optional Wc-build tail ----
// BM=MQ*32, BN=NQ*32; 8 waves = (MQ*NQ) spatial quadrants x KG K-groups.
// BK=128; 4-buf ring, depth-2 prefetch, counted vmcnt, ONE s_barrier/step.
// Staging: linear LDS dest + inverse-swizzled global SOURCE + swizzled READ
// (16 slots/row XOR row&15).
// Epilogue KG=2: symmetric kg exchange then expand split r<8/r>=8 across kg.
// KG=4: 2-round reduction to kg0.
// Tail (wcT != nullptr): grid-strided elementwise build of the NEXT layer's
// combined weight matrix -- runs after this block's output is done; ordering
// vs the consumer is by kernel completion.
template <int MQ, int NQ, int KG, bool EXPAND>
__global__ __launch_bounds__(512) void gemmW(
    const u16* __restrict__ A0, const u16* __restrict__ B0,
    const float* __restrict__ bias, const float* __restrict__ grid,
    void* __restrict__ outv, int M, int N, int K, int nsteps,
    const float* __restrict__ coefT, const float* __restrict__ sbT,
    const float* __restrict__ spT, const float* __restrict__ maskT,
    u16* __restrict__ wcT, int NT) {
  static_assert(MQ * NQ * KG == 8, "8 waves");
  constexpr int BM = MQ * 32, BN = NQ * 32;
  constexpr int ASZ = BM * 128;              // u16
  constexpr int BUF_U16 = (BM + BN) * 128;
  constexpr int LPT = (BM + BN) * 16 / 512;  // gloads per thread per stage
  constexpr int SPK = 8 / KG;                // K-16 slices per kg
  __shared__ __align__(16) u16 smu[4 * BUF_U16];

  const int tid = threadIdx.x;
  const int lane = tid & 63;
  const int wid = tid >> 6;
  const int q = wid % (MQ * NQ);
  const int kg = wid / (MQ * NQ);
  const int mq = (NQ == 2) ? (q >> 1) : q;
  const int nq = (NQ == 2) ? (q & 1) : 0;

  // XCD-aware swizzle (grid sizes are multiples of 8)
  const int nb = N / BN;
  const int nwg = (M / BM) * nb;
  const int bid = blockIdx.x;
  const int swz = (bid & 7) * (nwg >> 3) + (bid >> 3);
  const int tm = (swz / nb) * BM;
  const int tn = (swz % nb) * BN;

  const u16* pA0 = A0 + (size_t)tm * K;
  const u16* pB0 = B0 + (size_t)tn * K;

  // chunk c: A if c < BM*16 (row c>>4) else B (row (c-BM*16)>>4); slot=c&15
  // sources k-group slot^(row&15).  LDS linear dest offset = c*16B.
  int srcO[LPT];
  bool isA[LPT];
#pragma unroll
  for (int k = 0; k < LPT; ++k) {
    int c = tid + k * 512;
    bool a = c < BM * 16;
    int r = a ? (c >> 4) : ((c - BM * 16) >> 4);
    int sl = c & 15;
    isA[k] = a;
    srcO[k] = r * K + (((sl ^ (r & 15)) & 15) << 3);  // u16 units
  }

  const int lr = lane & 31;
  const int khf = lane >> 5;

  // swizzled LDS read offsets (u16): row*128 + ((slot^(row&15))&15)*8,
  // slot = slice*2 + khf, slice = kg*SPK + s
  int offA[SPK], offB[SPK];
#pragma unroll
  for (int s = 0; s < SPK; ++s) {
    int slice = kg * SPK + s;
    int rowA = mq * 32 + lr;
    int rowB = nq * 32 + lr;
    offA[s] = rowA * 128 + ((((slice * 2 + khf) ^ (rowA & 15)) & 15) << 3);
    offB[s] = rowB * 128 + ((((slice * 2 + khf) ^ (rowB & 15)) & 15) << 3);
  }

  auto stage = [&](int buf, int step) {
    int kk = step << 7;
    u16* sb = smu + buf * BUF_U16;
#pragma unroll
    for (int k = 0; k < LPT; ++k)
      gload16((isA[k] ? pA0 : pB0) + srcO[k] + kk, sb + (k * 512 + wid * 64) * 8);
  };

  f32x16 acc0 = {}, acc1 = {};
  stage(0, 0);
  stage(1, 1);
  for (int i = 0; i < nsteps; ++i) {
    if (i + 2 < nsteps) {
      stage((i + 2) & 3, i + 2);
      vmwait<2 * LPT>();  // my LPT loads for buf[i&3] landed (2 stages in flight)
    } else if (i + 1 < nsteps) {
      vmwait<LPT>();
    } else {
      vmwait<0>();
    }
    __builtin_amdgcn_sched_barrier(0);
    __builtin_amdgcn_s_barrier();  // everyone's buf-i loads landed;
                                   // also fences reads of buf[(i+2)&3] (iter i-2)
    __builtin_amdgcn_sched_barrier(0);

    const u16* sb = smu + (i & 3) * BUF_U16;
    bf16x8 af[SPK], bfr[SPK];
#pragma unroll
    for (int s = 0; s < SPK; ++s) {
      af[s] = *(const bf16x8*)(sb + offA[s]);
      bfr[s] = *(const bf16x8*)(sb + ASZ + offB[s]);
    }
#pragma unroll
    for (int s = 0; s < SPK; ++s) {
      f32x16& ac = (s & 1) ? acc1 : acc0;  // 2 chains for MFMA ILP
      ac = __builtin_amdgcn_mfma_f32_32x32x16_bf16(af[s], bfr[s], ac, 0, 0, 0);
    }
  }
  f32x16 accv = acc0 + acc1;

  // C/D layout (m74/m101): col = lane&31, row = (r&3) + 8*(r>>2) + 4*(lane>>5)
  const int rbase = 4 * khf;
  const int rowq = mq * 32, colq = nq * 32;

  float* Fr = (float*)smu;
  if constexpr (KG == 2) {
    // symmetric exchange: both kgs end up with the full sum (f32 + commutative)
    __syncthreads();
#pragma unroll
    for (int r = 0; r < 16; ++r) {
      int row = rowq + rbase + (r & 3) + 8 * (r >> 2);
      Fr[kg * (BM * BN) + row * BN + colq + lr] = accv[r];
    }
    __syncthreads();
#pragma unroll
    for (int r = 0; r < 16; ++r) {
      int row = rowq + rbase + (r & 3) + 8 * (r >> 2);
      accv[r] += Fr[(1 - kg) * (BM * BN) + row * BN + colq + lr];
    }
  } else {
    // 2-round reduction to kg0 (R12-proven)
    __syncthreads();
    if (kg >= 2) {
#pragma unroll
      for (int r = 0; r < 16; ++r) {
        int row = rowq + rbase + (r & 3) + 8 * (r >> 2);
        Fr[(kg - 2) * (BM * BN) + row * BN + colq + lr] = accv[r];
      }
    }
    __syncthreads();
    if (kg < 2) {
#pragma unroll
      for (int r = 0; r < 16; ++r) {
        int row = rowq + rbase + (r & 3) + 8 * (r >> 2);
        accv[r] += Fr[kg * (BM * BN) + row * BN + colq + lr];
      }
    }
    __syncthreads();
    if (kg == 1) {
#pragma unroll
      for (int r = 0; r < 16; ++r) {
        int row = rowq + rbase + (r & 3) + 8 * (r >> 2);
        Fr[row * BN + colq + lr] = accv[r];
      }
    }
    __syncthreads();
    if (kg == 0) {
#pragma unroll
      for (int r = 0; r < 16; ++r) {
        int row = rowq + rbase + (r & 3) + 8 * (r >> 2);
        accv[r] += Fr[row * BN + colq + lr];
      }
    }
  }

  if constexpr (EXPAND) {
    Spl sp;
    spl_init(grid, sp);
    __syncthreads();  // Fr reads done before F-tile overwrite
    u16* Fl = smu;
    {
      int col = colq + lr;
      float bv = bias ? bias[tn + col] : 0.0f;
      // split the serial spline chain across kg: kg0 -> r<8, kg1 -> r>=8
      const int r0 = kg * 8, r1 = r0 + 8;
#pragma unroll
      for (int r = 0; r < 16; ++r) {
        if (r >= r0 && r < r1) {
          int row = rowq + rbase + (r & 3) + 8 * (r >> 2);
          expand_one(accv[r] + bv, sp, Fl + (size_t)row * (BN * 9) + col * 9);
        }
      }
    }
    __syncthreads();
    // coalesced copy-out: BM x (BN*9) bf16 in 16B chunks, all 512 threads
    u16* Fout = (u16*)outv;
    constexpr int RB = BN * 9 / 8;
    constexpr int CH = BM * RB;
    const size_t fstride = (size_t)N * 9;
    for (int ch = tid; ch < CH; ch += 512) {
      int r = ch / RB, o = ch - r * RB;
      *(u16x8*)(Fout + (size_t)(tm + r) * fstride + (size_t)tn * 9 + o * 8) =
          *(const u16x8*)(Fl + (size_t)ch * 8);
    }
  } else {
    if (kg == 0) {
      float* Cp = (float*)outv;
      const int cbase = tn + colq + lr;
#pragma unroll
      for (int r = 0; r < 16; ++r) {
        int row = tm + rowq + rbase + (r & 3) + 8 * (r >> 2);
        Cp[(size_t)row * N + cbase] = accv[r];
      }
    }
  }

  // ---- tail: build next layer's Wc (grid-strided, 512 threads/block) ----
  if (wcT) {
    const int units = NT * K2L / 512;
    for (int u = bid; u < units; u += (int)gridDim.x)
      wc_one(coefT, sbT, spT, maskT, wcT, NT, u * 512 + tid);
  }
}

extern "C" void kernel_launch(void* const* d_in, const int* in_sizes, int n_in,
                              void* d_out, int out_size, void* d_ws, size_t ws_size,
                              hipStream_t stream) {
  (void)in_sizes; (void)n_in; (void)out_size; (void)ws_size;
  const float* x     = (const float*)d_in[0];   // 4096x1024
  const float* W1    = (const float*)d_in[1];   // 256x1024
  const float* b1    = (const float*)d_in[2];   // 256
  const float* grid1 = (const float*)d_in[3];   // 256x12 (rows identical)
  const float* coef1 = (const float*)d_in[4];   // 256x256x8
  const float* sb1   = (const float*)d_in[5];
  const float* sp1   = (const float*)d_in[6];
  const float* mask1 = (const float*)d_in[7];
  const float* grid2 = (const float*)d_in[8];
  const float* coef2 = (const float*)d_in[9];   // 256x128x8
  const float* sb2   = (const float*)d_in[10];
  const float* sp2   = (const float*)d_in[11];
  const float* mask2 = (const float*)d_in[12];
  float* outp = (float*)d_out;

  char* ws = (char*)d_ws;
  size_t off = 0;
  auto alloc = [&](size_t bytes) {
    char* p = ws + off;
    off += (bytes + 255) & ~(size_t)255;
    return (void*)p;
  };
  u16* xs_hi = (u16*)alloc((size_t)4096 * 1024 * 2);
  u16* w1_hi = (u16*)alloc((size_t)256 * 1024 * 2);
  u16* wc1   = (u16*)alloc((size_t)256 * K2L * 2);
  u16* wc2   = (u16*)alloc((size_t)128 * K2L * 2);
  u16* F1    = (u16*)alloc((size_t)4096 * K2L * 2);
  u16* F2    = (u16*)alloc((size_t)4096 * K2L * 2);

  // slim prep: bf16-cast x + W1 only
  prep_split_kernel<<<4352, 256, 0, stream>>>(x, W1, xs_hi, w1_hi);

  // L1: F1 = expand(x_bf @ W1_bf^T + b1); K=1024 -> 8 steps; tail builds Wc1
  gemmW<2, 2, 2, true><<<256, 512, 0, stream>>>(
      xs_hi, w1_hi, b1, grid1, F1, 4096, 256, 1024, 8,
      coef1, sb1, sp1, mask1, wc1, 256);

  // L2: F2 = expand(F1 @ Wc1^T); K=2304 -> 18 steps; tail builds Wc2
  gemmW<2, 2, 2, true><<<256, 512, 0, stream>>>(
      F1, wc1, nullptr, grid2, F2, 4096, 256, 2304, 18,
      coef2, sb2, sp2, mask2, wc2, 128);

  // L3: out = F2 @ Wc2^T; K=2304, N=128; BM=64 BN=32 -> grid 256; no tail
  gemmW<2, 1, 4, false><<<256, 512, 0, stream>>>(
      F2, wc2, nullptr, nullptr, outp, 4096, 128, 2304, 18,
      nullptr, nullptr, nullptr, nullptr, nullptr, 0);
}

// Round 19
// 57.541 us; speedup vs baseline: 1.0689x; 1.0197x over previous
//
#include <hip/hip_runtime.h>
#include <math.h>

typedef unsigned short u16;
typedef u16 u16x4 __attribute__((ext_vector_type(4)));
typedef u16 u16x8 __attribute__((ext_vector_type(8)));
typedef float f32x4 __attribute__((ext_vector_type(4)));
typedef float f32x16 __attribute__((ext_vector_type(16)));
typedef __bf16 bf16x8 __attribute__((ext_vector_type(8)));

#define KC 8
#define K2L 2304  // 256*9

__device__ __forceinline__ u16 f2bf_rne(float f) {
  unsigned u = __float_as_uint(f);
  u += 0x7FFFu + ((u >> 16) & 1u);
  return (u16)(u >> 16);
}

// async global->LDS, 16B/lane; LDS dest is the WAVE-UNIFORM base (HW adds lane*16)
__device__ __forceinline__ void gload16(const u16* g, u16* l) {
  __builtin_amdgcn_global_load_lds(
      (const __attribute__((address_space(1))) unsigned*)g,
      (__attribute__((address_space(3))) unsigned*)l, 16, 0, 0);
}
template <int N>
__device__ __forceinline__ void vmwait() {
  if constexpr (N == 0)      asm volatile("s_waitcnt vmcnt(0)" ::: "memory");
  else if constexpr (N == 3) asm volatile("s_waitcnt vmcnt(3)" ::: "memory");
  else if constexpr (N == 4) asm volatile("s_waitcnt vmcnt(4)" ::: "memory");
  else if constexpr (N == 6) asm volatile("s_waitcnt vmcnt(6)" ::: "memory");
  else if constexpr (N == 8) asm volatile("s_waitcnt vmcnt(8)" ::: "memory");
  else static_assert(N == 0, "unsupported vmcnt literal");
}

// ---- merged prep: bf16-cast x, bf16-cast W1, build Wc1, Wc2 ----
__device__ __forceinline__ void split4hi(const float* X, u16* hi, int i) {
  f32x4 v = ((const f32x4*)X)[i];
  u16x4 h;
#pragma unroll
  for (int c = 0; c < 4; ++c) h[c] = f2bf_rne(v[c]);
  ((u16x4*)hi)[i] = h;
}
__device__ __forceinline__ void wc_one(const float* coef, const float* sb, const float* sp,
                                       const float* mask, u16* W, int N, int idx) {
  int o = idx / K2L;
  int r = idx - o * K2L;
  int i = r / 9;
  int c = r - i * 9;
  int io = i * N + o;
  float m = mask[io];
  float v = (c == 0) ? m * sb[io] : m * sp[io] * coef[(size_t)io * KC + (c - 1)];
  W[idx] = f2bf_rne(v);
}

__global__ void prep_kernel(const float* __restrict__ x, const float* __restrict__ W1,
                            const float* __restrict__ coef1, const float* __restrict__ sb1,
                            const float* __restrict__ sp1, const float* __restrict__ mask1,
                            const float* __restrict__ coef2, const float* __restrict__ sb2,
                            const float* __restrict__ sp2, const float* __restrict__ mask2,
                            u16* __restrict__ xs_hi, u16* __restrict__ w1_hi,
                            u16* __restrict__ wc1, u16* __restrict__ wc2) {
  const int b = blockIdx.x, tid = threadIdx.x;
  if (b < 4096) {
    split4hi(x, xs_hi, b * 256 + tid);
  } else if (b < 4096 + 256) {
    split4hi(W1, w1_hi, (b - 4096) * 256 + tid);
  } else if (b < 4096 + 256 + 2304) {
    wc_one(coef1, sb1, sp1, mask1, wc1, 256, (b - 4352) * 256 + tid);
  } else {
    wc_one(coef2, sb2, sp2, mask2, wc2, 128, (b - 6656) * 256 + tid);
  }
}

// ---- spline tables + divide-free expand ----
struct Spl {
  float g[12];
  float d1[11], d2[10], d3[9];
};
__device__ __forceinline__ void spl_init(const float* __restrict__ grid, Spl& sp) {
#pragma unroll
  for (int j = 0; j < 12; ++j) sp.g[j] = grid[j];
#pragma unroll
  for (int j = 0; j < 11; ++j) sp.d1[j] = 1.0f / (sp.g[j + 1] - sp.g[j]);
#pragma unroll
  for (int j = 0; j < 10; ++j) sp.d2[j] = 1.0f / (sp.g[j + 2] - sp.g[j]);
#pragma unroll
  for (int j = 0; j < 9; ++j) sp.d3[j] = 1.0f / (sp.g[j + 3] - sp.g[j]);
}
__device__ __forceinline__ void expand_one(float v, const Spl& sp, u16* dst) {
  float Bv[11];
#pragma unroll
  for (int j = 0; j < 11; ++j) Bv[j] = (v >= sp.g[j] && v < sp.g[j + 1]) ? 1.0f : 0.0f;
#pragma unroll
  for (int j = 0; j < 10; ++j)
    Bv[j] = (v - sp.g[j]) * sp.d1[j] * Bv[j] + (sp.g[j + 2] - v) * sp.d1[j + 1] * Bv[j + 1];
#pragma unroll
  for (int j = 0; j < 9; ++j)
    Bv[j] = (v - sp.g[j]) * sp.d2[j] * Bv[j] + (sp.g[j + 3] - v) * sp.d2[j + 1] * Bv[j + 1];
#pragma unroll
  for (int j = 0; j < 8; ++j)
    Bv[j] = (v - sp.g[j]) * sp.d3[j] * Bv[j] + (sp.g[j + 4] - v) * sp.d3[j + 1] * Bv[j + 1];
  dst[0] = f2bf_rne(v / (1.0f + __expf(-v)));  // silu
#pragma unroll
  for (int k = 0; k < 8; ++k) dst[1 + k] = f2bf_rne(Bv[k]);
}

// ---- 8-wave MFMA GEMM (R11/R14-proven pipeline) ----
// BM=MQ*32, BN=NQ*32; 8 waves = (MQ*NQ) spatial quadrants x KG K-groups.
// BK=128; 4-buf ring, depth-2 prefetch, counted vmcnt, ONE s_barrier/step.
// Staging: linear LDS dest + inverse-swizzled global SOURCE + swizzled READ
// (16 slots/row XOR row&15).
// Epilogue KG=2: SYMMETRIC kg exchange (both add; f32 commutative -> identical
// sums) so BOTH kg groups hold the result, then expand split r<8 / r>=8 across
// kg -> half the serial spline chain.  KG=4: 2-round reduction to kg0.
template <int MQ, int NQ, int KG, bool EXPAND>
__global__ __launch_bounds__(512) void gemmW(
    const u16* __restrict__ A0, const u16* __restrict__ B0,
    const float* __restrict__ bias, const float* __restrict__ grid,
    void* __restrict__ outv, int M, int N, int K, int nsteps) {
  static_assert(MQ * NQ * KG == 8, "8 waves");
  constexpr int BM = MQ * 32, BN = NQ * 32;
  constexpr int ASZ = BM * 128;              // u16
  constexpr int BUF_U16 = (BM + BN) * 128;
  constexpr int LPT = (BM + BN) * 16 / 512;  // gloads per thread per stage
  constexpr int SPK = 8 / KG;                // K-16 slices per kg
  __shared__ __align__(16) u16 smu[4 * BUF_U16];

  const int tid = threadIdx.x;
  const int lane = tid & 63;
  const int wid = tid >> 6;
  const int q = wid % (MQ * NQ);
  const int kg = wid / (MQ * NQ);
  const int mq = (NQ == 2) ? (q >> 1) : q;
  const int nq = (NQ == 2) ? (q & 1) : 0;

  // XCD-aware swizzle (grid sizes are multiples of 8)
  const int nb = N / BN;
  const int nwg = (M / BM) * nb;
  const int bid = blockIdx.x;
  const int swz = (bid & 7) * (nwg >> 3) + (bid >> 3);
  const int tm = (swz / nb) * BM;
  const int tn = (swz % nb) * BN;

  const u16* pA0 = A0 + (size_t)tm * K;
  const u16* pB0 = B0 + (size_t)tn * K;

  // chunk c: A if c < BM*16 (row c>>4) else B (row (c-BM*16)>>4); slot=c&15
  // sources k-group slot^(row&15).  LDS linear dest offset = c*16B.
  int srcO[LPT];
  bool isA[LPT];
#pragma unroll
  for (int k = 0; k < LPT; ++k) {
    int c = tid + k * 512;
    bool a = c < BM * 16;
    int r = a ? (c >> 4) : ((c - BM * 16) >> 4);
    int sl = c & 15;
    isA[k] = a;
    srcO[k] = r * K + (((sl ^ (r & 15)) & 15) << 3);  // u16 units
  }

  const int lr = lane & 31;
  const int khf = lane >> 5;

  // swizzled LDS read offsets (u16): row*128 + ((slot^(row&15))&15)*8,
  // slot = slice*2 + khf, slice = kg*SPK + s
  int offA[SPK], offB[SPK];
#pragma unroll
  for (int s = 0; s < SPK; ++s) {
    int slice = kg * SPK + s;
    int rowA = mq * 32 + lr;
    int rowB = nq * 32 + lr;
    offA[s] = rowA * 128 + ((((slice * 2 + khf) ^ (rowA & 15)) & 15) << 3);
    offB[s] = rowB * 128 + ((((slice * 2 + khf) ^ (rowB & 15)) & 15) << 3);
  }

  auto stage = [&](int buf, int step) {
    int kk = step << 7;
    u16* sb = smu + buf * BUF_U16;
#pragma unroll
    for (int k = 0; k < LPT; ++k)
      gload16((isA[k] ? pA0 : pB0) + srcO[k] + kk, sb + (k * 512 + wid * 64) * 8);
  };

  f32x16 acc0 = {}, acc1 = {};
  stage(0, 0);
  stage(1, 1);
  for (int i = 0; i < nsteps; ++i) {
    if (i + 2 < nsteps) {
      stage((i + 2) & 3, i + 2);
      vmwait<2 * LPT>();  // my LPT loads for buf[i&3] landed (2 stages in flight)
    } else if (i + 1 < nsteps) {
      vmwait<LPT>();
    } else {
      vmwait<0>();
    }
    __builtin_amdgcn_sched_barrier(0);
    __builtin_amdgcn_s_barrier();  // everyone's buf-i loads landed;
                                   // also fences reads of buf[(i+2)&3] (iter i-2)
    __builtin_amdgcn_sched_barrier(0);

    const u16* sb = smu + (i & 3) * BUF_U16;
    bf16x8 af[SPK], bfr[SPK];
#pragma unroll
    for (int s = 0; s < SPK; ++s) {
      af[s] = *(const bf16x8*)(sb + offA[s]);
      bfr[s] = *(const bf16x8*)(sb + ASZ + offB[s]);
    }
#pragma unroll
    for (int s = 0; s < SPK; ++s) {
      f32x16& ac = (s & 1) ? acc1 : acc0;  // 2 chains for MFMA ILP
      ac = __builtin_amdgcn_mfma_f32_32x32x16_bf16(af[s], bfr[s], ac, 0, 0, 0);
    }
  }
  f32x16 accv = acc0 + acc1;

  // C/D layout (m74/m101): col = lane&31, row = (r&3) + 8*(r>>2) + 4*(lane>>5)
  const int rbase = 4 * khf;
  const int rowq = mq * 32, colq = nq * 32;

  float* Fr = (float*)smu;
  if constexpr (KG == 2) {
    // symmetric exchange: both kgs end up with the full sum (f32 + commutative)
    __syncthreads();
#pragma unroll
    for (int r = 0; r < 16; ++r) {
      int row = rowq + rbase + (r & 3) + 8 * (r >> 2);
      Fr[kg * (BM * BN) + row * BN + colq + lr] = accv[r];
    }
    __syncthreads();
#pragma unroll
    for (int r = 0; r < 16; ++r) {
      int row = rowq + rbase + (r & 3) + 8 * (r >> 2);
      accv[r] += Fr[(1 - kg) * (BM * BN) + row * BN + colq + lr];
    }
  } else {
    // 2-round reduction to kg0 (R12-proven)
    __syncthreads();
    if (kg >= 2) {
#pragma unroll
      for (int r = 0; r < 16; ++r) {
        int row = rowq + rbase + (r & 3) + 8 * (r >> 2);
        Fr[(kg - 2) * (BM * BN) + row * BN + colq + lr] = accv[r];
      }
    }
    __syncthreads();
    if (kg < 2) {
#pragma unroll
      for (int r = 0; r < 16; ++r) {
        int row = rowq + rbase + (r & 3) + 8 * (r >> 2);
        accv[r] += Fr[kg * (BM * BN) + row * BN + colq + lr];
      }
    }
    __syncthreads();
    if (kg == 1) {
#pragma unroll
      for (int r = 0; r < 16; ++r) {
        int row = rowq + rbase + (r & 3) + 8 * (r >> 2);
        Fr[row * BN + colq + lr] = accv[r];
      }
    }
    __syncthreads();
    if (kg == 0) {
#pragma unroll
      for (int r = 0; r < 16; ++r) {
        int row = rowq + rbase + (r & 3) + 8 * (r >> 2);
        accv[r] += Fr[row * BN + colq + lr];
      }
    }
  }

  if constexpr (EXPAND) {
    Spl sp;
    spl_init(grid, sp);
    __syncthreads();  // Fr reads done before F-tile overwrite
    u16* Fl = smu;
    {
      int col = colq + lr;
      float bv = bias ? bias[tn + col] : 0.0f;
      // split the serial spline chain across kg: kg0 -> r<8, kg1 -> r>=8
      const int r0 = kg * 8, r1 = r0 + 8;
#pragma unroll
      for (int r = 0; r < 16; ++r) {
        if (r >= r0 && r < r1) {
          int row = rowq + rbase + (r & 3) + 8 * (r >> 2);
          expand_one(accv[r] + bv, sp, Fl + (size_t)row * (BN * 9) + col * 9);
        }
      }
    }
    __syncthreads();
    // coalesced copy-out: BM x (BN*9) bf16 in 16B chunks, all 512 threads
    u16* Fout = (u16*)outv;
    constexpr int RB = BN * 9 / 8;
    constexpr int CH = BM * RB;
    const size_t fstride = (size_t)N * 9;
    for (int ch = tid; ch < CH; ch += 512) {
      int r = ch / RB, o = ch - r * RB;
      *(u16x8*)(Fout + (size_t)(tm + r) * fstride + (size_t)tn * 9 + o * 8) =
          *(const u16x8*)(Fl + (size_t)ch * 8);
    }
  } else {
    if (kg == 0) {
      float* Cp = (float*)outv;
      const int cbase = tn + colq + lr;
#pragma unroll
      for (int r = 0; r < 16; ++r) {
        int row = tm + rowq + rbase + (r & 3) + 8 * (r >> 2);
        Cp[(size_t)row * N + cbase] = accv[r];
      }
    }
  }
}

extern "C" void kernel_launch(void* const* d_in, const int* in_sizes, int n_in,
                              void* d_out, int out_size, void* d_ws, size_t ws_size,
                              hipStream_t stream) {
  (void)in_sizes; (void)n_in; (void)out_size; (void)ws_size;
  const float* x     = (const float*)d_in[0];   // 4096x1024
  const float* W1    = (const float*)d_in[1];   // 256x1024
  const float* b1    = (const float*)d_in[2];   // 256
  const float* grid1 = (const float*)d_in[3];   // 256x12 (rows identical)
  const float* coef1 = (const float*)d_in[4];   // 256x256x8
  const float* sb1   = (const float*)d_in[5];
  const float* sp1   = (const float*)d_in[6];
  const float* mask1 = (const float*)d_in[7];
  const float* grid2 = (const float*)d_in[8];
  const float* coef2 = (const float*)d_in[9];   // 256x128x8
  const float* sb2   = (const float*)d_in[10];
  const float* sp2   = (const float*)d_in[11];
  const float* mask2 = (const float*)d_in[12];
  float* outp = (float*)d_out;

  char* ws = (char*)d_ws;
  size_t off = 0;
  auto alloc = [&](size_t bytes) {
    char* p = ws + off;
    off += (bytes + 255) & ~(size_t)255;
    return (void*)p;
  };
  u16* xs_hi  = (u16*)alloc((size_t)4096 * 1024 * 2);
  u16* w1_hi  = (u16*)alloc((size_t)256 * 1024 * 2);
  u16* wc1    = (u16*)alloc((size_t)256 * K2L * 2);
  u16* wc2    = (u16*)alloc((size_t)128 * K2L * 2);
  u16* F1     = (u16*)alloc((size_t)4096 * K2L * 2);
  u16* F2     = (u16*)alloc((size_t)4096 * K2L * 2);

  // merged prep (all bf16 casts + Wc builds)
  prep_kernel<<<7808, 256, 0, stream>>>(x, W1, coef1, sb1, sp1, mask1,
                                        coef2, sb2, sp2, mask2,
                                        xs_hi, w1_hi, wc1, wc2);

  // L1: F1 = expand(x_bf @ W1_bf^T + b1); K=1024 -> 8 steps; grid 256
  gemmW<2, 2, 2, true><<<256, 512, 0, stream>>>(
      xs_hi, w1_hi, b1, grid1, F1, 4096, 256, 1024, 8);

  // L2: F2 = expand(F1 @ Wc1^T); K=2304 -> 18 steps; grid 256
  gemmW<2, 2, 2, true><<<256, 512, 0, stream>>>(
      F1, wc1, nullptr, grid2, F2, 4096, 256, 2304, 18);

  // L3: out = F2 @ Wc2^T; K=2304, N=128; BM=64 BN=32 -> grid 256
  gemmW<2, 1, 4, false><<<256, 512, 0, stream>>>(
      F2, wc2, nullptr, nullptr, outp, 4096, 128, 2304, 18);
}